// Round 8
// baseline (954.921 us; speedup 1.0000x reference)
//
#include <hip/hip_runtime.h>
#include <hip/hip_cooperative_groups.h>

namespace cgx = cooperative_groups;

static constexpr int NN  = 6144;
static constexpr int NE  = 98304;
static constexpr int NF  = 128;
static constexpr int NT  = 16;
static constexpr int MN  = 10;
static constexpr int NCG = 5;
static constexpr int NSK = 50;
static constexpr int WPR = NN / 32;
static constexpr int TPB = 768;
static constexpr int NBLK = 256;
static constexpr int RPT = NN / TPB;   // 8 rows/thread
static constexpr int NW  = TPB / 64;   // 12 waves

static_assert(TPB * RPT == NN, "row mapping");

// workspace layout (float elements); BM (setup-only) aliases T+C+D region
static constexpr size_t OFF_M   = 0;                              // fp32 [NT][NN][10]
static constexpr size_t OFF_T   = OFF_M  + (size_t)NT * NN * MN;  // u32 bf16-pairs [NT][NN][5]
static constexpr size_t OFF_C   = OFF_T  + (size_t)NT * NN * 5;
static constexpr size_t OFF_D   = OFF_C  + (size_t)NT * NN * 5;
static constexpr size_t OFF_RS  = OFF_D  + (size_t)NT * NN * 5;
static constexpr size_t OFF_DEG = OFF_RS + NN;
static constexpr size_t OFF_CI  = OFF_DEG + NN;                   // ushort[2*NE] in NE floats
static constexpr size_t OFF_NNZ = OFF_CI + NE;

static constexpr int LDS_E   = NN * 5 * 4;     // 122880 B: dd planes (interleaved pairs)
static constexpr int LDS_SP  = TPB * 11 * 4;   // 33792 B: reduction scatter (stride 11)
static constexpr int LDS_DYN = LDS_E + LDS_SP; // 156672 B

typedef unsigned u8v __attribute__((ext_vector_type(8)));   // one plane: rows k=0..7

__device__ __forceinline__ unsigned f2bf(float f) {            // fp32 -> bf16 (rne)
    unsigned u = __float_as_uint(f);
    return (u + 0x7fffu + ((u >> 16) & 1u)) >> 16;
}
__device__ __forceinline__ unsigned packbf(float a, float b) { return f2bf(a) | (f2bf(b) << 16); }
__device__ __forceinline__ float bflo(unsigned w) { return __uint_as_float(w << 16); }
__device__ __forceinline__ float bfhi(unsigned w) { return __uint_as_float(w & 0xffff0000u); }

// unpack/pack a row (k constant after unroll) between the 5 plane-vectors and e[10]
#define ROW_UNPACK(k, e) do { \
    unsigned w0 = EV0[k], w1 = EV1[k], w2 = EV2[k], w3 = EV3[k], w4 = EV4[k]; \
    e[0]=bflo(w0); e[1]=bfhi(w0); e[2]=bflo(w1); e[3]=bfhi(w1); \
    e[4]=bflo(w2); e[5]=bfhi(w2); e[6]=bflo(w3); e[7]=bfhi(w3); \
    e[8]=bflo(w4); e[9]=bfhi(w4); } while (0)
#define ROW_PACK(k, e) do { \
    EV0[k]=packbf(e[0],e[1]); EV1[k]=packbf(e[2],e[3]); EV2[k]=packbf(e[4],e[5]); \
    EV3[k]=packbf(e[6],e[7]); EV4[k]=packbf(e[8],e[9]); } while (0)

extern __shared__ char sMem[];

__global__ __launch_bounds__(TPB, 3) void tfgw_kernel(
    const float* __restrict__ x, const void* __restrict__ eiv,
    const float* __restrict__ tpl, const float* __restrict__ tf,
    const float* __restrict__ q0, const float* __restrict__ a0,
    float* __restrict__ out, float* __restrict__ W)
{
    __shared__ float sC2[MN * MN];
    __shared__ float sq[MN], scq[MN], sqC2[MN], sv[MN], sCv[MN], sNSQ[MN];
    __shared__ float sRed[3 * NW];
    __shared__ float sBC[2];
    __shared__ float sDots[4];

    const int tid = threadIdx.x;
    const int bid = blockIdx.x;

    unsigned* BM    = (unsigned*)(W + OFF_T);   // aliased; dead after setup
    int* rowst      = (int*)(W + OFF_RS);
    int* degi       = (int*)(W + OFF_DEG);
    unsigned short* colix = (unsigned short*)(W + OFF_CI);
    int* nnzc       = (int*)(W + OFF_NNZ);
    float* Mw  = W + OFF_M;
    unsigned* Tg = (unsigned*)(W + OFF_T);
    unsigned* Cg = (unsigned*)(W + OFF_C);
    unsigned* Dg = (unsigned*)(W + OFF_D);

    unsigned* PL01 = (unsigned*)sMem;           // dd planes 0&1 interleaved
    unsigned* PL23 = PL01 + 2 * NN;
    unsigned* PL4  = PL01 + 4 * NN;
    float* sP      = (float*)(sMem + LDS_E);    // [TPB*11]

    const float alpha  = 1.f / (1.f + __expf(-a0[0]));
    const float invn   = 1.f / (float)NN;
    const float alpha2 = 2.f * alpha;
    const float oma    = 1.f - alpha;

    cgx::grid_group grid = cgx::this_grid();

    // ---- P0: zero bitmap + nnz ----
    for (int idx = bid * TPB + tid; idx < NN * WPR; idx += NBLK * TPB) BM[idx] = 0u;
    if (bid == 0 && tid == 0) *nnzc = 0;
    grid.sync();

    // ---- P1: adjacency bits + feature cost M (sTF overlays sMem) ----
    {
        const unsigned* uw = (const unsigned*)eiv;
        const bool is64 = (uw[1] == 0u && uw[3] == 0u && uw[5] == 0u);
        for (int e = bid * TPB + tid; e < NE; e += NBLK * TPB) {
            int s, d;
            if (is64) {
                s = (int)((const long long*)eiv)[e];
                d = (int)((const long long*)eiv)[NE + e];
            } else {
                s = ((const int*)eiv)[e];
                d = ((const int*)eiv)[NE + e];
            }
            atomicOr(&BM[(size_t)s * WPR + (d >> 5)], 1u << (d & 31));
            atomicOr(&BM[(size_t)d * WPR + (s >> 5)], 1u << (s & 31));
        }
        float* sTF = (float*)sMem;
        const int t = bid >> 4, rb = bid & 15;
        for (int k = tid; k < MN * NF; k += TPB) sTF[k] = tf[t * MN * NF + k];
        __syncthreads();
        if (tid < MN) {
            float s = 0.f;
            for (int k = 0; k < NF; ++k) { float v = sTF[tid * NF + k]; s += v * v; }
            sNSQ[tid] = s;
        }
        __syncthreads();
        if (tid < 384) {
            const int i = rb * 384 + tid;
            const float4* x4 = (const float4*)(x + (size_t)i * NF);
            const float4* t4 = (const float4*)sTF;
            float acc[MN]; float xn = 0.f;
            #pragma unroll
            for (int j = 0; j < MN; ++j) acc[j] = 0.f;
            for (int k4 = 0; k4 < NF / 4; ++k4) {
                float4 xv = x4[k4];
                xn += xv.x * xv.x + xv.y * xv.y + xv.z * xv.z + xv.w * xv.w;
                #pragma unroll
                for (int j = 0; j < MN; ++j) {
                    float4 tv = t4[j * (NF / 4) + k4];
                    acc[j] += xv.x * tv.x + xv.y * tv.y + xv.z * tv.z + xv.w * tv.w;
                }
            }
            float* Mrow = Mw + (size_t)t * NN * MN + (size_t)i * MN;
            #pragma unroll
            for (int j = 0; j < MN; ++j) Mrow[j] = xn + sNSQ[j] - 2.f * acc[j];
        }
    }
    grid.sync();

    // ---- P2: degrees + CSR (ushort cols) ----
    {
        const int i = bid * TPB + tid;
        if (i < NN) {
            int cnt = 0;
            for (int w = 0; w < WPR; ++w) cnt += __popc(BM[(size_t)i * WPR + w]);
            int st = atomicAdd(nnzc, cnt);
            rowst[i] = st; degi[i] = cnt;
            int p = st;
            for (int w = 0; w < WPR; ++w) {
                unsigned m = BM[(size_t)i * WPR + w];
                while (m) { int b = __ffs(m) - 1; m &= m - 1; colix[p++] = (unsigned short)((w << 5) + b); }
            }
        }
    }
    grid.sync();     // last grid sync

    if (bid >= NT) return;

    // ================= block t owns template t =================
    const int t = bid;
    float* Mb = Mw + (size_t)t * NN * MN;
    unsigned* Tb = Tg + (size_t)t * NN * 5;
    unsigned* Cb = Cg + (size_t)t * NN * 5;
    unsigned* Db = Dg + (size_t)t * NN * 5;

    if (tid == 0) {
        float qv[MN]; float qm = -1e30f;
        for (int j = 0; j < MN; ++j) { qv[j] = q0[t * MN + j]; qm = fmaxf(qm, qv[j]); }
        float qs = 0.f;
        for (int j = 0; j < MN; ++j) { qv[j] = __expf(qv[j] - qm); qs += qv[j]; }
        for (int j = 0; j < MN; ++j) { qv[j] /= qs; sq[j] = qv[j]; }
        for (int j = 0; j < MN; ++j) {
            float s2 = 0.f, s1 = 0.f;
            for (int k = 0; k < MN; ++k) {
                float cjk = tpl[t * MN * MN + j * MN + k];
                s2 += cjk * cjk * qv[k];
                s1 += tpl[t * MN * MN + k * MN + j] * qv[k];
            }
            scq[j] = s2; sqC2[j] = s1;
        }
    }
    for (int k = tid; k < MN * MN; k += TPB) sC2[k] = tpl[t * MN * MN + k];
    __syncthreads();

    u8v EV0, EV1, EV2, EV3, EV4;   // 5 planes x 8 rows, bf16 pairs (E, later dd)
    float uu[RPT];

    for (int cgi = 0; cgi < NCG; ++cgi) {
        // ---- tau from previous dots; tau==0 (cgi>0) => fixed point ----
        if (tid == 0) {
            float tau = 0.f;
            if (cgi > 0) {
                float a = -2.f * alpha * sDots[3];
                float b = oma * sDots[0] + alpha * (sDots[1] - 4.f * sDots[2]);
                if (a > 0.f) tau = fminf(fmaxf(-b / (2.f * a + 1e-16f), 0.f), 1.f);
                else         tau = (a + b < 0.f) ? 1.f : 0.f;
            }
            sBC[0] = tau;
        }
        __syncthreads();
        const float tau = sBC[0];
        if (cgi > 0 && tau == 0.f) break;

        // ---- Phase A: update T,C (bf16 globals; dd from registers); g -> EV ----
        float gmax = 0.f;
        #pragma unroll
        for (int k = 0; k < RPT; ++k) {
            const int r = tid + k * TPB;
            const float cp = (float)degi[r] * invn;
            const size_t b5 = (size_t)r * 5;
            float C[MN];
            if (cgi == 0) {
                #pragma unroll
                for (int h = 0; h < 5; ++h) {
                    unsigned tw = packbf(sq[2*h] * invn, sq[2*h+1] * invn);
                    unsigned cw = packbf(cp * sqC2[2*h], cp * sqC2[2*h+1]);
                    Tb[b5 + h] = tw; Cb[b5 + h] = cw;
                    C[2*h] = bflo(cw); C[2*h+1] = bfhi(cw);
                }
            } else {
                float dd[MN];
                ROW_UNPACK(k, dd);
                #pragma unroll
                for (int h = 0; h < 5; ++h) {
                    unsigned tw = Tb[b5 + h], cw = Cb[b5 + h], Dw = Db[b5 + h];
                    float T0 = bflo(tw) + tau * dd[2*h];
                    float T1 = bfhi(tw) + tau * dd[2*h+1];
                    float C0 = bflo(cw) + tau * bflo(Dw);
                    float C1v = bfhi(cw) + tau * bfhi(Dw);
                    unsigned ntw = packbf(T0, T1), ncw = packbf(C0, C1v);
                    Tb[b5 + h] = ntw; Cb[b5 + h] = ncw;
                    C[2*h] = bflo(ncw); C[2*h+1] = bfhi(ncw);
                }
            }
            float g[MN];
            #pragma unroll
            for (int h = 0; h < 5; ++h) {
                float2 mv = *(const float2*)(Mb + (size_t)r * MN + 2*h);
                g[2*h]   = oma * mv.x + alpha2 * (cp + scq[2*h]   - 2.f * C[2*h]);
                g[2*h+1] = oma * mv.y + alpha2 * (cp + scq[2*h+1] - 2.f * C[2*h+1]);
                gmax = fmaxf(gmax, fmaxf(__builtin_fabsf(g[2*h]), __builtin_fabsf(g[2*h+1])));
            }
            ROW_PACK(k, g);
        }
        #pragma unroll
        for (int d = 32; d; d >>= 1) gmax = fmaxf(gmax, __shfl_xor(gmax, d));
        if ((tid & 63) == 0) sRed[tid >> 6] = gmax;
        __syncthreads();
        if (tid == 0) {
            float m = sRed[0];
            for (int w = 1; w < NW; ++w) m = fmaxf(m, sRed[w]);
            sBC[1] = 1.f / (0.05f * m + 1e-8f);
        }
        __syncthreads();
        const float invreg = sBC[1];

        // ---- Phase B: E = exp(-g*invreg), registers only ----
        #pragma unroll
        for (int k = 0; k < RPT; ++k) {
            float g[MN];
            ROW_UNPACK(k, g);
            float e[MN];
            #pragma unroll
            for (int j = 0; j < MN; ++j) e[j] = __expf(-g[j] * invreg);
            ROW_PACK(k, e);
        }

        // ---- Sinkhorn iter 0 (u = 1) ----
        {
            float a[MN];
            #pragma unroll
            for (int j = 0; j < MN; ++j) a[j] = 0.f;
            #pragma unroll
            for (int k = 0; k < RPT; ++k) {
                float e[MN];
                ROW_UNPACK(k, e);
                #pragma unroll
                for (int j = 0; j < MN; ++j) a[j] += e[j];
            }
            #pragma unroll
            for (int j = 0; j < MN; ++j) sP[tid * 11 + j] = a[j];
            __syncthreads();
            if (tid < 640) {
                const int j = tid >> 6, c = tid & 63;
                float s = 0.f;
                #pragma unroll
                for (int kk = 0; kk < NW; ++kk) s += sP[(c + (kk << 6)) * 11 + j];
                #pragma unroll
                for (int d = 32; d; d >>= 1) s += __shfl_xor(s, d);
                if (c == 0) { sv[j] = sq[j] / s; sCv[j] = 0.f; }
            }
            __syncthreads();
        }

        // ---- Sinkhorn fused (u,v) x50, early exit on v fixed point ----
        for (int it = 1; it <= NSK; ++it) {
            float vv[MN];
            #pragma unroll
            for (int j = 0; j < MN; ++j) vv[j] = sv[j];
            float a[MN];
            #pragma unroll
            for (int j = 0; j < MN; ++j) a[j] = 0.f;
            #pragma unroll
            for (int k = 0; k < RPT; ++k) {
                float e[MN];
                ROW_UNPACK(k, e);
                float R = 0.f;
                #pragma unroll
                for (int j = 0; j < MN; ++j) R += e[j] * vv[j];
                const float u = invn * __builtin_amdgcn_rcpf(R);
                uu[k] = u;
                #pragma unroll
                for (int j = 0; j < MN; ++j) a[j] += e[j] * u;
            }
            #pragma unroll
            for (int j = 0; j < MN; ++j) sP[tid * 11 + j] = a[j];
            __syncthreads();
            if (tid < 640) {
                const int j = tid >> 6, c = tid & 63;
                float s = 0.f;
                #pragma unroll
                for (int kk = 0; kk < NW; ++kk) s += sP[(c + (kk << 6)) * 11 + j];
                #pragma unroll
                for (int d = 32; d; d >>= 1) s += __shfl_xor(s, d);
                if (c == 0) {
                    float vold = sv[j];
                    float vnew = sq[j] / s;
                    sCv[j] = (__builtin_fabsf(vnew - vold) <= 3e-6f * vnew) ? 1.f : 0.f;
                    sv[j] = vnew;
                }
            }
            __syncthreads();
            float cs = 0.f;
            #pragma unroll
            for (int j = 0; j < MN; ++j) cs += sCv[j];
            if (cs == 10.f) break;
        }

        // ---- dT phase: dd = u*E*v - T; dots; EV <- dd; PL <- dd (for gather) ----
        {
            float vv[MN];
            #pragma unroll
            for (int j = 0; j < MN; ++j) vv[j] = sv[j];
            float sMdT = 0.f, sCdT = 0.f, sCTdT = 0.f;
            #pragma unroll
            for (int k = 0; k < RPT; ++k) {
                const int r = tid + k * TPB;
                const float cp = (float)degi[r] * invn;
                const size_t b5 = (size_t)r * 5;
                const float u = uu[k];
                float e[MN], dd[MN];
                ROW_UNPACK(k, e);
                #pragma unroll
                for (int h = 0; h < 5; ++h) {
                    unsigned tw = Tb[b5 + h], cw = Cb[b5 + h];
                    float2 mv = *(const float2*)(Mb + (size_t)r * MN + 2*h);
                    float d0 = u * e[2*h]   * vv[2*h]   - bflo(tw);
                    float d1 = u * e[2*h+1] * vv[2*h+1] - bfhi(tw);
                    dd[2*h] = d0; dd[2*h+1] = d1;
                    sMdT  += mv.x * d0 + mv.y * d1;
                    sCdT  += (cp + scq[2*h]) * d0 + (cp + scq[2*h+1]) * d1;
                    sCTdT += bflo(cw) * d0 + bfhi(cw) * d1;
                }
                ROW_PACK(k, dd);
                *(uint2*)(PL01 + 2 * r) = make_uint2(EV0[k], EV1[k]);
                *(uint2*)(PL23 + 2 * r) = make_uint2(EV2[k], EV3[k]);
                PL4[r] = EV4[k];
            }
            #pragma unroll
            for (int d = 32; d; d >>= 1) {
                sMdT  += __shfl_xor(sMdT, d);
                sCdT  += __shfl_xor(sCdT, d);
                sCTdT += __shfl_xor(sCTdT, d);
            }
            if ((tid & 63) == 0) {
                const int w = tid >> 6;
                sRed[w] = sMdT; sRed[NW + w] = sCdT; sRed[2*NW + w] = sCTdT;
            }
            __syncthreads();   // dots staged AND dd planes visible block-wide
            if (tid == 0) {
                float r0 = 0.f, r1 = 0.f, r2 = 0.f;
                for (int w = 0; w < NW; ++w) { r0 += sRed[w]; r1 += sRed[NW+w]; r2 += sRed[2*NW+w]; }
                sDots[0] = r0; sDots[1] = r1; sDots[2] = r2;
            }
        }

        // ---- SpMM: D = C1 dT C2 (gather dd planes), sA = <D,dd>; Db <- bf16 ----
        {
            float dot = 0.f;
            #pragma unroll
            for (int k = 0; k < RPT; ++k) {
                const int r = tid + k * TPB;
                float y[MN];
                #pragma unroll
                for (int j = 0; j < MN; ++j) y[j] = 0.f;
                const int st = rowst[r], dg = degi[r];
                const unsigned short* cl = colix + st;
                for (int e = 0; e < dg; ++e) {
                    const int j = cl[e];
                    uint2 a01 = *(const uint2*)(PL01 + 2 * j);
                    uint2 a23 = *(const uint2*)(PL23 + 2 * j);
                    unsigned a4 = PL4[j];
                    y[0] += bflo(a01.x); y[1] += bfhi(a01.x);
                    y[2] += bflo(a01.y); y[3] += bfhi(a01.y);
                    y[4] += bflo(a23.x); y[5] += bfhi(a23.x);
                    y[6] += bflo(a23.y); y[7] += bfhi(a23.y);
                    y[8] += bflo(a4);    y[9] += bfhi(a4);
                }
                float dd[MN];
                ROW_UNPACK(k, dd);
                #pragma unroll
                for (int h = 0; h < 5; ++h) {
                    float o0 = 0.f, o1 = 0.f;
                    #pragma unroll
                    for (int j = 0; j < MN; ++j) {
                        o0 += y[j] * sC2[j * MN + 2*h];
                        o1 += y[j] * sC2[j * MN + 2*h + 1];
                    }
                    dot += o0 * dd[2*h] + o1 * dd[2*h+1];
                    Db[(size_t)r * 5 + h] = packbf(o0, o1);
                }
            }
            #pragma unroll
            for (int d = 32; d; d >>= 1) dot += __shfl_xor(dot, d);
            if ((tid & 63) == 0) sRed[tid >> 6] = dot;
            __syncthreads();
            if (tid == 0) {
                float s = 0.f;
                for (int w = 0; w < NW; ++w) s += sRed[w];
                sDots[3] = s;
            }
            __syncthreads();
        }
    }

    // ---- F: final tau + objective (T,C,D from bf16 globals; dd from registers) ----
    if (tid == 0) {
        float a = -2.f * alpha * sDots[3];
        float b = oma * sDots[0] + alpha * (sDots[1] - 4.f * sDots[2]);
        float tau;
        if (a > 0.f) tau = fminf(fmaxf(-b / (2.f * a + 1e-16f), 0.f), 1.f);
        else         tau = (a + b < 0.f) ? 1.f : 0.f;
        sBC[0] = tau;
    }
    __syncthreads();
    {
        const float tau = sBC[0];
        float gw = 0.f, wass = 0.f;
        #pragma unroll
        for (int k = 0; k < RPT; ++k) {
            const int r = tid + k * TPB;
            const float cp = (float)degi[r] * invn;
            const size_t b5 = (size_t)r * 5;
            float dd[MN];
            ROW_UNPACK(k, dd);
            #pragma unroll
            for (int h = 0; h < 5; ++h) {
                unsigned tw = Tb[b5 + h], cw = Cb[b5 + h], Dw = Db[b5 + h];
                float2 mv = *(const float2*)(Mb + (size_t)r * MN + 2*h);
                float Tf0 = bflo(tw) + tau * dd[2*h];
                float Tf1 = bfhi(tw) + tau * dd[2*h+1];
                float Cf0 = bflo(cw) + tau * bflo(Dw);
                float Cf1 = bfhi(cw) + tau * bfhi(Dw);
                gw   += (cp + scq[2*h]   - 2.f * Cf0) * Tf0
                      + (cp + scq[2*h+1] - 2.f * Cf1) * Tf1;
                wass += mv.x * Tf0 + mv.y * Tf1;
            }
        }
        #pragma unroll
        for (int d = 32; d; d >>= 1) {
            gw   += __shfl_xor(gw, d);
            wass += __shfl_xor(wass, d);
        }
        if ((tid & 63) == 0) { sRed[tid >> 6] = gw; sRed[NW + (tid >> 6)] = wass; }
        __syncthreads();
        if (tid == 0) {
            float g = 0.f, ws = 0.f;
            for (int w = 0; w < NW; ++w) { g += sRed[w]; ws += sRed[NW + w]; }
            out[t] = oma * ws + alpha * g;
        }
    }
}

extern "C" void kernel_launch(void* const* d_in, const int* in_sizes, int n_in,
                              void* d_out, int out_size, void* d_ws, size_t ws_size,
                              hipStream_t stream) {
    const float* x   = (const float*)d_in[0];
    const void*  ei  = d_in[1];
    const float* tpl = (const float*)d_in[2];
    const float* tfp = (const float*)d_in[3];
    const float* q0  = (const float*)d_in[4];
    const float* a0  = (const float*)d_in[5];
    float* outp = (float*)d_out;
    float* Wp   = (float*)d_ws;
    (void)hipFuncSetAttribute(reinterpret_cast<const void*>(&tfgw_kernel),
                              hipFuncAttributeMaxDynamicSharedMemorySize, LDS_DYN);
    void* args[] = { &x, &ei, &tpl, &tfp, &q0, &a0, &outp, &Wp };
    hipLaunchCooperativeKernel(reinterpret_cast<const void*>(&tfgw_kernel),
                               dim3(NBLK), dim3(TPB), args, LDS_DYN, stream);
}

// Round 9
// 711.950 us; speedup vs baseline: 1.3413x; 1.3413x over previous
//
#include <hip/hip_runtime.h>
#include <hip/hip_cooperative_groups.h>

namespace cgx = cooperative_groups;

static constexpr int NN  = 6144;
static constexpr int NE  = 98304;
static constexpr int NF  = 128;
static constexpr int NT  = 16;
static constexpr int MN  = 10;
static constexpr int NCG = 5;
static constexpr int NSK = 50;
static constexpr int WPR = NN / 32;
static constexpr int TPB = 768;
static constexpr int NBLK = 256;
static constexpr int RPT = NN / TPB;   // 8 rows/thread
static constexpr int NW  = TPB / 64;   // 12 waves

static_assert(TPB * RPT == NN, "row mapping");

// workspace layout (float elements); BM (setup-only) aliases T+C+D region
static constexpr size_t OFF_M   = 0;                              // fp32 [NT][NN][10]
static constexpr size_t OFF_T   = OFF_M  + (size_t)NT * NN * MN;  // u32 bf16-pairs [NT][NN][5]
static constexpr size_t OFF_C   = OFF_T  + (size_t)NT * NN * 5;
static constexpr size_t OFF_D   = OFF_C  + (size_t)NT * NN * 5;
static constexpr size_t OFF_RS  = OFF_D  + (size_t)NT * NN * 5;
static constexpr size_t OFF_DEG = OFF_RS + NN;
static constexpr size_t OFF_CI  = OFF_DEG + NN;                   // ushort[2*NE] in NE floats
static constexpr size_t OFF_NNZ = OFF_CI + NE;

// LDS: rows as uint4 (cols 0-7) + u32 (cols 8-9); packed reduction buffer
static constexpr int LDS_PL  = NN * 20;          // 122880 B
static constexpr int LDS_SP  = TPB * 7 * 4;      // 21504 B (stride 7: conflict-free)
static constexpr int LDS_DYN = LDS_PL + LDS_SP;  // 144384 B

__device__ __forceinline__ unsigned f2bf(float f) {            // fp32 -> bf16 (rne)
    unsigned u = __float_as_uint(f);
    return (u + 0x7fffu + ((u >> 16) & 1u)) >> 16;
}
__device__ __forceinline__ unsigned packbf(float a, float b) { return f2bf(a) | (f2bf(b) << 16); }
__device__ __forceinline__ float bflo(unsigned w) { return __uint_as_float(w << 16); }
__device__ __forceinline__ float bfhi(unsigned w) { return __uint_as_float(w & 0xffff0000u); }

extern __shared__ char sMem[];

__global__ __launch_bounds__(TPB) void tfgw_kernel(
    const float* __restrict__ x, const void* __restrict__ eiv,
    const float* __restrict__ tpl, const float* __restrict__ tf,
    const float* __restrict__ q0, const float* __restrict__ a0,
    float* __restrict__ out, float* __restrict__ W)
{
    __shared__ float sC2[MN * MN];
    __shared__ float sq[MN], scq[MN], sqC2[MN], sv[MN], sCv[5], sNSQ[MN];
    __shared__ float sRed[3 * NW];
    __shared__ float sBC[2];
    __shared__ float sDots[4];

    const int tid = threadIdx.x;
    const int bid = blockIdx.x;

    unsigned* BM    = (unsigned*)(W + OFF_T);   // aliased; dead after setup
    int* rowst      = (int*)(W + OFF_RS);
    int* degi       = (int*)(W + OFF_DEG);
    unsigned short* colix = (unsigned short*)(W + OFF_CI);
    int* nnzc       = (int*)(W + OFF_NNZ);
    float* Mw  = W + OFF_M;
    unsigned* Tg = (unsigned*)(W + OFF_T);
    unsigned* Cg = (unsigned*)(W + OFF_C);
    unsigned* Dg = (unsigned*)(W + OFF_D);

    uint4*    PL4x = (uint4*)sMem;                        // [NN]: cols 0-7
    unsigned* PL1x = (unsigned*)(sMem + NN * 16);         // [NN]: cols 8-9
    unsigned* sPp  = (unsigned*)(sMem + LDS_PL);          // [TPB*7] packed partials

    const float alpha  = 1.f / (1.f + __expf(-a0[0]));
    const float invn   = 1.f / (float)NN;
    const float alpha2 = 2.f * alpha;
    const float oma    = 1.f - alpha;

    cgx::grid_group grid = cgx::this_grid();

    // ---- P0: zero bitmap + nnz ----
    for (int idx = bid * TPB + tid; idx < NN * WPR; idx += NBLK * TPB) BM[idx] = 0u;
    if (bid == 0 && tid == 0) *nnzc = 0;
    grid.sync();

    // ---- P1: adjacency bits + feature cost M (sTF overlays sMem) ----
    {
        const unsigned* uw = (const unsigned*)eiv;
        const bool is64 = (uw[1] == 0u && uw[3] == 0u && uw[5] == 0u);
        for (int e = bid * TPB + tid; e < NE; e += NBLK * TPB) {
            int s, d;
            if (is64) {
                s = (int)((const long long*)eiv)[e];
                d = (int)((const long long*)eiv)[NE + e];
            } else {
                s = ((const int*)eiv)[e];
                d = ((const int*)eiv)[NE + e];
            }
            atomicOr(&BM[(size_t)s * WPR + (d >> 5)], 1u << (d & 31));
            atomicOr(&BM[(size_t)d * WPR + (s >> 5)], 1u << (s & 31));
        }
        float* sTF = (float*)sMem;
        const int t = bid >> 4, rb = bid & 15;
        for (int k = tid; k < MN * NF; k += TPB) sTF[k] = tf[t * MN * NF + k];
        __syncthreads();
        if (tid < MN) {
            float s = 0.f;
            for (int k = 0; k < NF; ++k) { float v = sTF[tid * NF + k]; s += v * v; }
            sNSQ[tid] = s;
        }
        __syncthreads();
        if (tid < 384) {
            const int i = rb * 384 + tid;
            const float4* x4 = (const float4*)(x + (size_t)i * NF);
            const float4* t4 = (const float4*)sTF;
            float acc[MN]; float xn = 0.f;
            #pragma unroll
            for (int j = 0; j < MN; ++j) acc[j] = 0.f;
            for (int k4 = 0; k4 < NF / 4; ++k4) {
                float4 xv = x4[k4];
                xn += xv.x * xv.x + xv.y * xv.y + xv.z * xv.z + xv.w * xv.w;
                #pragma unroll
                for (int j = 0; j < MN; ++j) {
                    float4 tv = t4[j * (NF / 4) + k4];
                    acc[j] += xv.x * tv.x + xv.y * tv.y + xv.z * tv.z + xv.w * tv.w;
                }
            }
            float* Mrow = Mw + (size_t)t * NN * MN + (size_t)i * MN;
            #pragma unroll
            for (int j = 0; j < MN; ++j) Mrow[j] = xn + sNSQ[j] - 2.f * acc[j];
        }
    }
    grid.sync();

    // ---- P2: degrees + CSR (ushort cols) ----
    {
        const int i = bid * TPB + tid;
        if (i < NN) {
            int cnt = 0;
            for (int w = 0; w < WPR; ++w) cnt += __popc(BM[(size_t)i * WPR + w]);
            int st = atomicAdd(nnzc, cnt);
            rowst[i] = st; degi[i] = cnt;
            int p = st;
            for (int w = 0; w < WPR; ++w) {
                unsigned m = BM[(size_t)i * WPR + w];
                while (m) { int b = __ffs(m) - 1; m &= m - 1; colix[p++] = (unsigned short)((w << 5) + b); }
            }
        }
    }
    grid.sync();     // last grid sync

    if (bid >= NT) return;

    // ================= block t owns template t =================
    const int t = bid;
    float* Mb = Mw + (size_t)t * NN * MN;
    unsigned* Tb = Tg + (size_t)t * NN * 5;
    unsigned* Cb = Cg + (size_t)t * NN * 5;
    unsigned* Db = Dg + (size_t)t * NN * 5;

    if (tid == 0) {
        float qv[MN]; float qm = -1e30f;
        for (int j = 0; j < MN; ++j) { qv[j] = q0[t * MN + j]; qm = fmaxf(qm, qv[j]); }
        float qs = 0.f;
        for (int j = 0; j < MN; ++j) { qv[j] = __expf(qv[j] - qm); qs += qv[j]; }
        for (int j = 0; j < MN; ++j) { qv[j] /= qs; sq[j] = qv[j]; }
        for (int j = 0; j < MN; ++j) {
            float s2 = 0.f, s1 = 0.f;
            for (int k = 0; k < MN; ++k) {
                float cjk = tpl[t * MN * MN + j * MN + k];
                s2 += cjk * cjk * qv[k];
                s1 += tpl[t * MN * MN + k * MN + j] * qv[k];
            }
            scq[j] = s2; sqC2[j] = s1;
        }
    }
    for (int k = tid; k < MN * MN; k += TPB) sC2[k] = tpl[t * MN * MN + k];
    __syncthreads();

    float uu[RPT];

    for (int cgi = 0; cgi < NCG; ++cgi) {
        // ---- tau from previous dots; tau==0 (cgi>0) => fixed point ----
        if (tid == 0) {
            float tau = 0.f;
            if (cgi > 0) {
                float a = -2.f * alpha * sDots[3];
                float b = oma * sDots[0] + alpha * (sDots[1] - 4.f * sDots[2]);
                if (a > 0.f) tau = fminf(fmaxf(-b / (2.f * a + 1e-16f), 0.f), 1.f);
                else         tau = (a + b < 0.f) ? 1.f : 0.f;
            }
            sBC[0] = tau;
        }
        __syncthreads();
        const float tau = sBC[0];
        if (cgi > 0 && tau == 0.f) break;

        // ---- Phase A: update T,C (bf16 globals; dd from planes); g -> planes ----
        float gmax = 0.f;
        #pragma unroll
        for (int k = 0; k < RPT; ++k) {
            const int r = tid + k * TPB;
            const float cp = (float)degi[r] * invn;
            const size_t b5 = (size_t)r * 5;
            float C[MN];
            if (cgi == 0) {
                #pragma unroll
                for (int h = 0; h < 5; ++h) {
                    unsigned tw = packbf(sq[2*h] * invn, sq[2*h+1] * invn);
                    unsigned cw = packbf(cp * sqC2[2*h], cp * sqC2[2*h+1]);
                    Tb[b5 + h] = tw; Cb[b5 + h] = cw;
                    C[2*h] = bflo(cw); C[2*h+1] = bfhi(cw);
                }
            } else {
                float dd[MN];
                uint4 a = PL4x[r]; unsigned b4 = PL1x[r];
                dd[0]=bflo(a.x); dd[1]=bfhi(a.x); dd[2]=bflo(a.y); dd[3]=bfhi(a.y);
                dd[4]=bflo(a.z); dd[5]=bfhi(a.z); dd[6]=bflo(a.w); dd[7]=bfhi(a.w);
                dd[8]=bflo(b4);  dd[9]=bfhi(b4);
                #pragma unroll
                for (int h = 0; h < 5; ++h) {
                    unsigned tw = Tb[b5 + h], cw = Cb[b5 + h], Dw = Db[b5 + h];
                    float T0 = bflo(tw) + tau * dd[2*h];
                    float T1 = bfhi(tw) + tau * dd[2*h+1];
                    float C0 = bflo(cw) + tau * bflo(Dw);
                    float C1v = bfhi(cw) + tau * bfhi(Dw);
                    unsigned ntw = packbf(T0, T1), ncw = packbf(C0, C1v);
                    Tb[b5 + h] = ntw; Cb[b5 + h] = ncw;
                    C[2*h] = bflo(ncw); C[2*h+1] = bfhi(ncw);
                }
            }
            float g[MN];
            #pragma unroll
            for (int h = 0; h < 5; ++h) {
                float2 mv = *(const float2*)(Mb + (size_t)r * MN + 2*h);
                g[2*h]   = oma * mv.x + alpha2 * (cp + scq[2*h]   - 2.f * C[2*h]);
                g[2*h+1] = oma * mv.y + alpha2 * (cp + scq[2*h+1] - 2.f * C[2*h+1]);
                gmax = fmaxf(gmax, fmaxf(__builtin_fabsf(g[2*h]), __builtin_fabsf(g[2*h+1])));
            }
            PL4x[r] = make_uint4(packbf(g[0],g[1]), packbf(g[2],g[3]),
                                 packbf(g[4],g[5]), packbf(g[6],g[7]));
            PL1x[r] = packbf(g[8], g[9]);
        }
        #pragma unroll
        for (int d = 32; d; d >>= 1) gmax = fmaxf(gmax, __shfl_xor(gmax, d));
        if ((tid & 63) == 0) sRed[tid >> 6] = gmax;
        __syncthreads();
        if (tid == 0) {
            float m = sRed[0];
            for (int w = 1; w < NW; ++w) m = fmaxf(m, sRed[w]);
            sBC[1] = 1.f / (0.05f * m + 1e-8f);
        }
        __syncthreads();
        const float invreg = sBC[1];

        // ---- Phase B: E = exp(-g*invreg), in place ----
        #pragma unroll
        for (int k = 0; k < RPT; ++k) {
            const int r = tid + k * TPB;
            uint4 a = PL4x[r]; unsigned b4 = PL1x[r];
            float g[MN];
            g[0]=bflo(a.x); g[1]=bfhi(a.x); g[2]=bflo(a.y); g[3]=bfhi(a.y);
            g[4]=bflo(a.z); g[5]=bfhi(a.z); g[6]=bflo(a.w); g[7]=bfhi(a.w);
            g[8]=bflo(b4);  g[9]=bfhi(b4);
            float e[MN];
            #pragma unroll
            for (int j = 0; j < MN; ++j) e[j] = __expf(-g[j] * invreg);
            PL4x[r] = make_uint4(packbf(e[0],e[1]), packbf(e[2],e[3]),
                                 packbf(e[4],e[5]), packbf(e[6],e[7]));
            PL1x[r] = packbf(e[8], e[9]);
        }
        __syncthreads();

        // ---- Sinkhorn iter 0 (u = 1) ----
        {
            float a[MN];
            #pragma unroll
            for (int j = 0; j < MN; ++j) a[j] = 0.f;
            #pragma unroll
            for (int k = 0; k < RPT; ++k) {
                const int r = tid + k * TPB;
                uint4 q = PL4x[r]; unsigned b4 = PL1x[r];
                a[0]+=bflo(q.x); a[1]+=bfhi(q.x); a[2]+=bflo(q.y); a[3]+=bfhi(q.y);
                a[4]+=bflo(q.z); a[5]+=bfhi(q.z); a[6]+=bflo(q.w); a[7]+=bfhi(q.w);
                a[8]+=bflo(b4);  a[9]+=bfhi(b4);
            }
            #pragma unroll
            for (int p = 0; p < 5; ++p) sPp[tid * 7 + p] = packbf(a[2*p], a[2*p+1]);
            __syncthreads();
            if (tid < 320) {
                const int p = tid >> 6, c = tid & 63;
                float s0 = 0.f, s1 = 0.f;
                #pragma unroll
                for (int kk = 0; kk < NW; ++kk) {
                    unsigned w = sPp[(c + (kk << 6)) * 7 + p];
                    s0 += bflo(w); s1 += bfhi(w);
                }
                #pragma unroll
                for (int d = 32; d; d >>= 1) { s0 += __shfl_xor(s0, d); s1 += __shfl_xor(s1, d); }
                if (c == 0) { sv[2*p] = sq[2*p] / s0; sv[2*p+1] = sq[2*p+1] / s1; sCv[p] = 0.f; }
            }
            __syncthreads();
        }

        // ---- Sinkhorn fused (u,v) x50, early exit on v fixed point ----
        for (int it = 1; it <= NSK; ++it) {
            float vv[MN];
            #pragma unroll
            for (int j = 0; j < MN; ++j) vv[j] = sv[j];
            float a[MN];
            #pragma unroll
            for (int j = 0; j < MN; ++j) a[j] = 0.f;
            #pragma unroll
            for (int k = 0; k < RPT; ++k) {
                const int r = tid + k * TPB;
                uint4 q = PL4x[r]; unsigned b4 = PL1x[r];
                float e[MN];
                e[0]=bflo(q.x); e[1]=bfhi(q.x); e[2]=bflo(q.y); e[3]=bfhi(q.y);
                e[4]=bflo(q.z); e[5]=bfhi(q.z); e[6]=bflo(q.w); e[7]=bfhi(q.w);
                e[8]=bflo(b4);  e[9]=bfhi(b4);
                float R = 0.f;
                #pragma unroll
                for (int j = 0; j < MN; ++j) R += e[j] * vv[j];
                const float u = invn * __builtin_amdgcn_rcpf(R);
                uu[k] = u;
                #pragma unroll
                for (int j = 0; j < MN; ++j) a[j] += e[j] * u;
            }
            #pragma unroll
            for (int p = 0; p < 5; ++p) sPp[tid * 7 + p] = packbf(a[2*p], a[2*p+1]);
            __syncthreads();
            if (tid < 320) {
                const int p = tid >> 6, c = tid & 63;
                float s0 = 0.f, s1 = 0.f;
                #pragma unroll
                for (int kk = 0; kk < NW; ++kk) {
                    unsigned w = sPp[(c + (kk << 6)) * 7 + p];
                    s0 += bflo(w); s1 += bfhi(w);
                }
                #pragma unroll
                for (int d = 32; d; d >>= 1) { s0 += __shfl_xor(s0, d); s1 += __shfl_xor(s1, d); }
                if (c == 0) {
                    float v0 = sq[2*p] / s0, v1 = sq[2*p+1] / s1;
                    float o0 = sv[2*p],     o1 = sv[2*p+1];
                    sCv[p] = (__builtin_fabsf(v0 - o0) <= 2e-4f * v0 &&
                              __builtin_fabsf(v1 - o1) <= 2e-4f * v1) ? 1.f : 0.f;
                    sv[2*p] = v0; sv[2*p+1] = v1;
                }
            }
            __syncthreads();
            if (sCv[0] + sCv[1] + sCv[2] + sCv[3] + sCv[4] == 5.f) break;
        }

        // ---- dT phase: dd = u*E*v - T; dots; planes <- dd(bf16) ----
        {
            float vv[MN];
            #pragma unroll
            for (int j = 0; j < MN; ++j) vv[j] = sv[j];
            float sMdT = 0.f, sCdT = 0.f, sCTdT = 0.f;
            #pragma unroll
            for (int k = 0; k < RPT; ++k) {
                const int r = tid + k * TPB;
                const float cp = (float)degi[r] * invn;
                const size_t b5 = (size_t)r * 5;
                const float u = uu[k];
                uint4 q = PL4x[r]; unsigned b4 = PL1x[r];
                float e[MN], dd[MN];
                e[0]=bflo(q.x); e[1]=bfhi(q.x); e[2]=bflo(q.y); e[3]=bfhi(q.y);
                e[4]=bflo(q.z); e[5]=bfhi(q.z); e[6]=bflo(q.w); e[7]=bfhi(q.w);
                e[8]=bflo(b4);  e[9]=bfhi(b4);
                #pragma unroll
                for (int h = 0; h < 5; ++h) {
                    unsigned tw = Tb[b5 + h], cw = Cb[b5 + h];
                    float2 mv = *(const float2*)(Mb + (size_t)r * MN + 2*h);
                    float d0 = u * e[2*h]   * vv[2*h]   - bflo(tw);
                    float d1 = u * e[2*h+1] * vv[2*h+1] - bfhi(tw);
                    dd[2*h] = d0; dd[2*h+1] = d1;
                    sMdT  += mv.x * d0 + mv.y * d1;
                    sCdT  += (cp + scq[2*h]) * d0 + (cp + scq[2*h+1]) * d1;
                    sCTdT += bflo(cw) * d0 + bfhi(cw) * d1;
                }
                PL4x[r] = make_uint4(packbf(dd[0],dd[1]), packbf(dd[2],dd[3]),
                                     packbf(dd[4],dd[5]), packbf(dd[6],dd[7]));
                PL1x[r] = packbf(dd[8], dd[9]);
            }
            #pragma unroll
            for (int d = 32; d; d >>= 1) {
                sMdT  += __shfl_xor(sMdT, d);
                sCdT  += __shfl_xor(sCdT, d);
                sCTdT += __shfl_xor(sCTdT, d);
            }
            if ((tid & 63) == 0) {
                const int w = tid >> 6;
                sRed[w] = sMdT; sRed[NW + w] = sCdT; sRed[2*NW + w] = sCTdT;
            }
            __syncthreads();   // dots staged AND dd planes visible block-wide
            if (tid == 0) {
                float r0 = 0.f, r1 = 0.f, r2 = 0.f;
                for (int w = 0; w < NW; ++w) { r0 += sRed[w]; r1 += sRed[NW+w]; r2 += sRed[2*NW+w]; }
                sDots[0] = r0; sDots[1] = r1; sDots[2] = r2;
            }
        }

        // ---- SpMM: D = C1 dT C2 (gather dd planes), sA = <D,dd>; Db <- bf16 ----
        {
            float dot = 0.f;
            #pragma unroll
            for (int k = 0; k < RPT; ++k) {
                const int r = tid + k * TPB;
                float y[MN];
                #pragma unroll
                for (int j = 0; j < MN; ++j) y[j] = 0.f;
                const int st = rowst[r], dg = degi[r];
                const unsigned short* cl = colix + st;
                for (int e = 0; e < dg; ++e) {
                    const int j = cl[e];
                    uint4 q = PL4x[j]; unsigned b4 = PL1x[j];
                    y[0] += bflo(q.x); y[1] += bfhi(q.x);
                    y[2] += bflo(q.y); y[3] += bfhi(q.y);
                    y[4] += bflo(q.z); y[5] += bfhi(q.z);
                    y[6] += bflo(q.w); y[7] += bfhi(q.w);
                    y[8] += bflo(b4);  y[9] += bfhi(b4);
                }
                uint4 q = PL4x[r]; unsigned b4 = PL1x[r];
                float dd[MN];
                dd[0]=bflo(q.x); dd[1]=bfhi(q.x); dd[2]=bflo(q.y); dd[3]=bfhi(q.y);
                dd[4]=bflo(q.z); dd[5]=bfhi(q.z); dd[6]=bflo(q.w); dd[7]=bfhi(q.w);
                dd[8]=bflo(b4);  dd[9]=bfhi(b4);
                #pragma unroll
                for (int h = 0; h < 5; ++h) {
                    float o0 = 0.f, o1 = 0.f;
                    #pragma unroll
                    for (int j = 0; j < MN; ++j) {
                        o0 += y[j] * sC2[j * MN + 2*h];
                        o1 += y[j] * sC2[j * MN + 2*h + 1];
                    }
                    dot += o0 * dd[2*h] + o1 * dd[2*h+1];
                    Db[(size_t)r * 5 + h] = packbf(o0, o1);
                }
            }
            #pragma unroll
            for (int d = 32; d; d >>= 1) dot += __shfl_xor(dot, d);
            if ((tid & 63) == 0) sRed[tid >> 6] = dot;
            __syncthreads();
            if (tid == 0) {
                float s = 0.f;
                for (int w = 0; w < NW; ++w) s += sRed[w];
                sDots[3] = s;
            }
            __syncthreads();
        }
    }

    // ---- F: final tau + objective (T,C,D from bf16 globals; dd from planes) ----
    if (tid == 0) {
        float a = -2.f * alpha * sDots[3];
        float b = oma * sDots[0] + alpha * (sDots[1] - 4.f * sDots[2]);
        float tau;
        if (a > 0.f) tau = fminf(fmaxf(-b / (2.f * a + 1e-16f), 0.f), 1.f);
        else         tau = (a + b < 0.f) ? 1.f : 0.f;
        sBC[0] = tau;
    }
    __syncthreads();
    {
        const float tau = sBC[0];
        float gw = 0.f, wass = 0.f;
        #pragma unroll
        for (int k = 0; k < RPT; ++k) {
            const int r = tid + k * TPB;
            const float cp = (float)degi[r] * invn;
            const size_t b5 = (size_t)r * 5;
            uint4 q = PL4x[r]; unsigned b4 = PL1x[r];
            float dd[MN];
            dd[0]=bflo(q.x); dd[1]=bfhi(q.x); dd[2]=bflo(q.y); dd[3]=bfhi(q.y);
            dd[4]=bflo(q.z); dd[5]=bfhi(q.z); dd[6]=bflo(q.w); dd[7]=bfhi(q.w);
            dd[8]=bflo(b4);  dd[9]=bfhi(b4);
            #pragma unroll
            for (int h = 0; h < 5; ++h) {
                unsigned tw = Tb[b5 + h], cw = Cb[b5 + h], Dw = Db[b5 + h];
                float2 mv = *(const float2*)(Mb + (size_t)r * MN + 2*h);
                float Tf0 = bflo(tw) + tau * dd[2*h];
                float Tf1 = bfhi(tw) + tau * dd[2*h+1];
                float Cf0 = bflo(cw) + tau * bflo(Dw);
                float Cf1 = bfhi(cw) + tau * bfhi(Dw);
                gw   += (cp + scq[2*h]   - 2.f * Cf0) * Tf0
                      + (cp + scq[2*h+1] - 2.f * Cf1) * Tf1;
                wass += mv.x * Tf0 + mv.y * Tf1;
            }
        }
        #pragma unroll
        for (int d = 32; d; d >>= 1) {
            gw   += __shfl_xor(gw, d);
            wass += __shfl_xor(wass, d);
        }
        if ((tid & 63) == 0) { sRed[tid >> 6] = gw; sRed[NW + (tid >> 6)] = wass; }
        __syncthreads();
        if (tid == 0) {
            float g = 0.f, ws = 0.f;
            for (int w = 0; w < NW; ++w) { g += sRed[w]; ws += sRed[NW + w]; }
            out[t] = oma * ws + alpha * g;
        }
    }
}

extern "C" void kernel_launch(void* const* d_in, const int* in_sizes, int n_in,
                              void* d_out, int out_size, void* d_ws, size_t ws_size,
                              hipStream_t stream) {
    const float* x   = (const float*)d_in[0];
    const void*  ei  = d_in[1];
    const float* tpl = (const float*)d_in[2];
    const float* tfp = (const float*)d_in[3];
    const float* q0  = (const float*)d_in[4];
    const float* a0  = (const float*)d_in[5];
    float* outp = (float*)d_out;
    float* Wp   = (float*)d_ws;
    (void)hipFuncSetAttribute(reinterpret_cast<const void*>(&tfgw_kernel),
                              hipFuncAttributeMaxDynamicSharedMemorySize, LDS_DYN);
    void* args[] = { &x, &ei, &tpl, &tfp, &q0, &a0, &outp, &Wp };
    hipLaunchCooperativeKernel(reinterpret_cast<const void*>(&tfgw_kernel),
                               dim3(NBLK), dim3(TPB), args, LDS_DYN, stream);
}

// Round 10
// 693.069 us; speedup vs baseline: 1.3778x; 1.0272x over previous
//
#include <hip/hip_runtime.h>
#include <hip/hip_cooperative_groups.h>

namespace cgx = cooperative_groups;

static constexpr int NN  = 6144;
static constexpr int NE  = 98304;
static constexpr int NF  = 128;
static constexpr int NT  = 16;
static constexpr int MN  = 10;
static constexpr int NCG = 5;
static constexpr int NSK = 50;
static constexpr int WPR = NN / 32;
static constexpr int TPB = 768;
static constexpr int NBLK = 256;
static constexpr int RPT = NN / TPB;   // 8 rows/thread
static constexpr int NW  = TPB / 64;   // 12 waves

static_assert(TPB * RPT == NN, "row mapping");

// workspace layout (float elements); BM (setup-only) aliases T+C+D region
static constexpr size_t OFF_M   = 0;                              // fp32 [NT][NN][10]
static constexpr size_t OFF_T   = OFF_M  + (size_t)NT * NN * MN;  // u32 bf16-pairs [NT][NN][5]
static constexpr size_t OFF_C   = OFF_T  + (size_t)NT * NN * 5;
static constexpr size_t OFF_D   = OFF_C  + (size_t)NT * NN * 5;
static constexpr size_t OFF_RS  = OFF_D  + (size_t)NT * NN * 5;
static constexpr size_t OFF_DEG = OFF_RS + NN;
static constexpr size_t OFF_CI  = OFF_DEG + NN;                   // ushort[2*NE] in NE floats
static constexpr size_t OFF_NNZ = OFF_CI + NE;

// LDS: rows as uint4 (cols 0-7) + u32 (cols 8-9); packed reduction buffer
static constexpr int LDS_PL  = NN * 20;          // 122880 B
static constexpr int LDS_SP  = TPB * 7 * 4;      // 21504 B (stride 7: conflict-free)
static constexpr int LDS_DYN = LDS_PL + LDS_SP;  // 144384 B

__device__ __forceinline__ unsigned f2bf(float f) {            // fp32 -> bf16 (rne)
    unsigned u = __float_as_uint(f);
    return (u + 0x7fffu + ((u >> 16) & 1u)) >> 16;
}
__device__ __forceinline__ unsigned packbf(float a, float b) { return f2bf(a) | (f2bf(b) << 16); }
__device__ __forceinline__ float bflo(unsigned w) { return __uint_as_float(w << 16); }
__device__ __forceinline__ float bfhi(unsigned w) { return __uint_as_float(w & 0xffff0000u); }

extern __shared__ char sMem[];

__global__ __launch_bounds__(TPB) void tfgw_kernel(
    const float* __restrict__ x, const void* __restrict__ eiv,
    const float* __restrict__ tpl, const float* __restrict__ tf,
    const float* __restrict__ q0, const float* __restrict__ a0,
    float* __restrict__ out, float* __restrict__ W)
{
    __shared__ float sC2[MN * MN];
    __shared__ float sq[MN], scq[MN], sqC2[MN], sNSQ[MN];
    __shared__ unsigned svp[5];        // v packed bf16-pairs (row threads read this)
    __shared__ float sVf[MN];          // v fp32 (reducer lanes only: convergence test)
    __shared__ float sCv[5];
    __shared__ float sRed[3 * NW];
    __shared__ float sBC[2];
    __shared__ float sDots[4];

    const int tid = threadIdx.x;
    const int bid = blockIdx.x;

    unsigned* BM    = (unsigned*)(W + OFF_T);   // aliased; dead after setup
    int* rowst      = (int*)(W + OFF_RS);
    int* degi       = (int*)(W + OFF_DEG);
    unsigned short* colix = (unsigned short*)(W + OFF_CI);
    int* nnzc       = (int*)(W + OFF_NNZ);
    float* Mw  = W + OFF_M;
    unsigned* Tg = (unsigned*)(W + OFF_T);
    unsigned* Cg = (unsigned*)(W + OFF_C);
    unsigned* Dg = (unsigned*)(W + OFF_D);

    uint4*    PL4x = (uint4*)sMem;                        // [NN]: cols 0-7
    unsigned* PL1x = (unsigned*)(sMem + NN * 16);         // [NN]: cols 8-9
    unsigned* sPp  = (unsigned*)(sMem + LDS_PL);          // [TPB*7] packed partials

    const float alpha  = 1.f / (1.f + __expf(-a0[0]));
    const float invn   = 1.f / (float)NN;
    const float alpha2 = 2.f * alpha;
    const float oma    = 1.f - alpha;

    cgx::grid_group grid = cgx::this_grid();

    // ---- P0: zero bitmap + nnz ----
    for (int idx = bid * TPB + tid; idx < NN * WPR; idx += NBLK * TPB) BM[idx] = 0u;
    if (bid == 0 && tid == 0) *nnzc = 0;
    grid.sync();

    // ---- P1: adjacency bits + feature cost M (sTF overlays sMem) ----
    {
        const unsigned* uw = (const unsigned*)eiv;
        const bool is64 = (uw[1] == 0u && uw[3] == 0u && uw[5] == 0u);
        for (int e = bid * TPB + tid; e < NE; e += NBLK * TPB) {
            int s, d;
            if (is64) {
                s = (int)((const long long*)eiv)[e];
                d = (int)((const long long*)eiv)[NE + e];
            } else {
                s = ((const int*)eiv)[e];
                d = ((const int*)eiv)[NE + e];
            }
            atomicOr(&BM[(size_t)s * WPR + (d >> 5)], 1u << (d & 31));
            atomicOr(&BM[(size_t)d * WPR + (s >> 5)], 1u << (s & 31));
        }
        float* sTF = (float*)sMem;
        const int t = bid >> 4, rb = bid & 15;
        for (int k = tid; k < MN * NF; k += TPB) sTF[k] = tf[t * MN * NF + k];
        __syncthreads();
        if (tid < MN) {
            float s = 0.f;
            for (int k = 0; k < NF; ++k) { float v = sTF[tid * NF + k]; s += v * v; }
            sNSQ[tid] = s;
        }
        __syncthreads();
        if (tid < 384) {
            const int i = rb * 384 + tid;
            const float4* x4 = (const float4*)(x + (size_t)i * NF);
            const float4* t4 = (const float4*)sTF;
            float acc[MN]; float xn = 0.f;
            #pragma unroll
            for (int j = 0; j < MN; ++j) acc[j] = 0.f;
            for (int k4 = 0; k4 < NF / 4; ++k4) {
                float4 xv = x4[k4];
                xn += xv.x * xv.x + xv.y * xv.y + xv.z * xv.z + xv.w * xv.w;
                #pragma unroll
                for (int j = 0; j < MN; ++j) {
                    float4 tv = t4[j * (NF / 4) + k4];
                    acc[j] += xv.x * tv.x + xv.y * tv.y + xv.z * tv.z + xv.w * tv.w;
                }
            }
            float* Mrow = Mw + (size_t)t * NN * MN + (size_t)i * MN;
            #pragma unroll
            for (int j = 0; j < MN; ++j) Mrow[j] = xn + sNSQ[j] - 2.f * acc[j];
        }
    }
    grid.sync();

    // ---- P2: degrees + CSR (ushort cols) ----
    {
        const int i = bid * TPB + tid;
        if (i < NN) {
            int cnt = 0;
            for (int w = 0; w < WPR; ++w) cnt += __popc(BM[(size_t)i * WPR + w]);
            int st = atomicAdd(nnzc, cnt);
            rowst[i] = st; degi[i] = cnt;
            int p = st;
            for (int w = 0; w < WPR; ++w) {
                unsigned m = BM[(size_t)i * WPR + w];
                while (m) { int b = __ffs(m) - 1; m &= m - 1; colix[p++] = (unsigned short)((w << 5) + b); }
            }
        }
    }
    grid.sync();     // last grid sync

    if (bid >= NT) return;

    // ================= block t owns template t =================
    const int t = bid;
    float* Mb = Mw + (size_t)t * NN * MN;
    unsigned* Tb = Tg + (size_t)t * NN * 5;
    unsigned* Cb = Cg + (size_t)t * NN * 5;
    unsigned* Db = Dg + (size_t)t * NN * 5;

    if (tid == 0) {
        float qv[MN]; float qm = -1e30f;
        for (int j = 0; j < MN; ++j) { qv[j] = q0[t * MN + j]; qm = fmaxf(qm, qv[j]); }
        float qs = 0.f;
        for (int j = 0; j < MN; ++j) { qv[j] = __expf(qv[j] - qm); qs += qv[j]; }
        for (int j = 0; j < MN; ++j) { qv[j] /= qs; sq[j] = qv[j]; }
        for (int j = 0; j < MN; ++j) {
            float s2 = 0.f, s1 = 0.f;
            for (int k = 0; k < MN; ++k) {
                float cjk = tpl[t * MN * MN + j * MN + k];
                s2 += cjk * cjk * qv[k];
                s1 += tpl[t * MN * MN + k * MN + j] * qv[k];
            }
            scq[j] = s2; sqC2[j] = s1;
        }
    }
    for (int k = tid; k < MN * MN; k += TPB) sC2[k] = tpl[t * MN * MN + k];
    __syncthreads();

    float uu[RPT];

    for (int cgi = 0; cgi < NCG; ++cgi) {
        // ---- tau from previous dots; tau==0 (cgi>0) => fixed point ----
        if (tid == 0) {
            float tau = 0.f;
            if (cgi > 0) {
                float a = -2.f * alpha * sDots[3];
                float b = oma * sDots[0] + alpha * (sDots[1] - 4.f * sDots[2]);
                if (a > 0.f) tau = fminf(fmaxf(-b / (2.f * a + 1e-16f), 0.f), 1.f);
                else         tau = (a + b < 0.f) ? 1.f : 0.f;
            }
            sBC[0] = tau;
        }
        __syncthreads();
        const float tau = sBC[0];
        if (cgi > 0 && tau == 0.f) break;

        // ---- Phase A: update T,C (bf16 globals; dd from planes); g -> planes ----
        float gmax = 0.f;
        #pragma unroll
        for (int k = 0; k < RPT; ++k) {
            const int r = tid + k * TPB;
            const float cp = (float)degi[r] * invn;
            const size_t b5 = (size_t)r * 5;
            float C[MN];
            if (cgi == 0) {
                #pragma unroll
                for (int h = 0; h < 5; ++h) {
                    unsigned tw = packbf(sq[2*h] * invn, sq[2*h+1] * invn);
                    unsigned cw = packbf(cp * sqC2[2*h], cp * sqC2[2*h+1]);
                    Tb[b5 + h] = tw; Cb[b5 + h] = cw;
                    C[2*h] = bflo(cw); C[2*h+1] = bfhi(cw);
                }
            } else {
                float dd[MN];
                uint4 a = PL4x[r]; unsigned b4 = PL1x[r];
                dd[0]=bflo(a.x); dd[1]=bfhi(a.x); dd[2]=bflo(a.y); dd[3]=bfhi(a.y);
                dd[4]=bflo(a.z); dd[5]=bfhi(a.z); dd[6]=bflo(a.w); dd[7]=bfhi(a.w);
                dd[8]=bflo(b4);  dd[9]=bfhi(b4);
                #pragma unroll
                for (int h = 0; h < 5; ++h) {
                    unsigned tw = Tb[b5 + h], cw = Cb[b5 + h], Dw = Db[b5 + h];
                    float T0 = bflo(tw) + tau * dd[2*h];
                    float T1 = bfhi(tw) + tau * dd[2*h+1];
                    float C0 = bflo(cw) + tau * bflo(Dw);
                    float C1v = bfhi(cw) + tau * bfhi(Dw);
                    unsigned ntw = packbf(T0, T1), ncw = packbf(C0, C1v);
                    Tb[b5 + h] = ntw; Cb[b5 + h] = ncw;
                    C[2*h] = bflo(ncw); C[2*h+1] = bfhi(ncw);
                }
            }
            float g[MN];
            #pragma unroll
            for (int h = 0; h < 5; ++h) {
                float2 mv = *(const float2*)(Mb + (size_t)r * MN + 2*h);
                g[2*h]   = oma * mv.x + alpha2 * (cp + scq[2*h]   - 2.f * C[2*h]);
                g[2*h+1] = oma * mv.y + alpha2 * (cp + scq[2*h+1] - 2.f * C[2*h+1]);
                gmax = fmaxf(gmax, fmaxf(__builtin_fabsf(g[2*h]), __builtin_fabsf(g[2*h+1])));
            }
            PL4x[r] = make_uint4(packbf(g[0],g[1]), packbf(g[2],g[3]),
                                 packbf(g[4],g[5]), packbf(g[6],g[7]));
            PL1x[r] = packbf(g[8], g[9]);
        }
        #pragma unroll
        for (int d = 32; d; d >>= 1) gmax = fmaxf(gmax, __shfl_xor(gmax, d));
        if ((tid & 63) == 0) sRed[tid >> 6] = gmax;
        __syncthreads();
        if (tid == 0) {
            float m = sRed[0];
            for (int w = 1; w < NW; ++w) m = fmaxf(m, sRed[w]);
            sBC[1] = 1.f / (0.05f * m + 1e-8f);
        }
        __syncthreads();
        const float invreg = sBC[1];

        // ---- Phase B: E = exp(-g*invreg), in place (own rows only; no barrier) ----
        #pragma unroll
        for (int k = 0; k < RPT; ++k) {
            const int r = tid + k * TPB;
            uint4 a = PL4x[r]; unsigned b4 = PL1x[r];
            float g[MN];
            g[0]=bflo(a.x); g[1]=bfhi(a.x); g[2]=bflo(a.y); g[3]=bfhi(a.y);
            g[4]=bflo(a.z); g[5]=bfhi(a.z); g[6]=bflo(a.w); g[7]=bfhi(a.w);
            g[8]=bflo(b4);  g[9]=bfhi(b4);
            float e[MN];
            #pragma unroll
            for (int j = 0; j < MN; ++j) e[j] = __expf(-g[j] * invreg);
            PL4x[r] = make_uint4(packbf(e[0],e[1]), packbf(e[2],e[3]),
                                 packbf(e[4],e[5]), packbf(e[6],e[7]));
            PL1x[r] = packbf(e[8], e[9]);
        }

        // ---- Sinkhorn iter 0 (u = 1) — only for cgi==0; else warm-start from prev v ----
        if (cgi == 0) {
            float a[MN];
            #pragma unroll
            for (int j = 0; j < MN; ++j) a[j] = 0.f;
            #pragma unroll
            for (int k = 0; k < RPT; ++k) {
                const int r = tid + k * TPB;
                uint4 q = PL4x[r]; unsigned b4 = PL1x[r];
                a[0]+=bflo(q.x); a[1]+=bfhi(q.x); a[2]+=bflo(q.y); a[3]+=bfhi(q.y);
                a[4]+=bflo(q.z); a[5]+=bfhi(q.z); a[6]+=bflo(q.w); a[7]+=bfhi(q.w);
                a[8]+=bflo(b4);  a[9]+=bfhi(b4);
            }
            #pragma unroll
            for (int p = 0; p < 5; ++p) sPp[tid * 7 + p] = packbf(a[2*p], a[2*p+1]);
            __syncthreads();
            if (tid < 320) {
                const int p = tid >> 6, c = tid & 63;
                float s0 = 0.f, s1 = 0.f;
                #pragma unroll
                for (int kk = 0; kk < NW; ++kk) {
                    unsigned w = sPp[(c + (kk << 6)) * 7 + p];
                    s0 += bflo(w); s1 += bfhi(w);
                }
                #pragma unroll
                for (int d = 32; d; d >>= 1) { s0 += __shfl_xor(s0, d); s1 += __shfl_xor(s1, d); }
                if (c == 0) {
                    float v0 = sq[2*p] / s0, v1 = sq[2*p+1] / s1;
                    svp[p] = packbf(v0, v1);
                    sVf[2*p] = v0; sVf[2*p+1] = v1;
                }
            }
            __syncthreads();
        }

        // ---- Sinkhorn fused (u,v) x50, early exit on v fixed point ----
        for (int it = 1; it <= NSK; ++it) {
            float vv[MN];
            #pragma unroll
            for (int p = 0; p < 5; ++p) {
                unsigned w = svp[p];
                vv[2*p] = bflo(w); vv[2*p+1] = bfhi(w);
            }
            float a[MN];
            #pragma unroll
            for (int j = 0; j < MN; ++j) a[j] = 0.f;
            #pragma unroll
            for (int k = 0; k < RPT; ++k) {
                const int r = tid + k * TPB;
                uint4 q = PL4x[r]; unsigned b4 = PL1x[r];
                float e[MN];
                e[0]=bflo(q.x); e[1]=bfhi(q.x); e[2]=bflo(q.y); e[3]=bfhi(q.y);
                e[4]=bflo(q.z); e[5]=bfhi(q.z); e[6]=bflo(q.w); e[7]=bfhi(q.w);
                e[8]=bflo(b4);  e[9]=bfhi(b4);
                float R = 0.f;
                #pragma unroll
                for (int j = 0; j < MN; ++j) R += e[j] * vv[j];
                const float u = invn * __builtin_amdgcn_rcpf(R);
                uu[k] = u;
                #pragma unroll
                for (int j = 0; j < MN; ++j) a[j] += e[j] * u;
            }
            #pragma unroll
            for (int p = 0; p < 5; ++p) sPp[tid * 7 + p] = packbf(a[2*p], a[2*p+1]);
            __syncthreads();
            if (tid < 320) {
                const int p = tid >> 6, c = tid & 63;
                float s0 = 0.f, s1 = 0.f;
                #pragma unroll
                for (int kk = 0; kk < NW; ++kk) {
                    unsigned w = sPp[(c + (kk << 6)) * 7 + p];
                    s0 += bflo(w); s1 += bfhi(w);
                }
                #pragma unroll
                for (int d = 32; d; d >>= 1) { s0 += __shfl_xor(s0, d); s1 += __shfl_xor(s1, d); }
                if (c == 0) {
                    float v0 = sq[2*p] / s0, v1 = sq[2*p+1] / s1;
                    float o0 = sVf[2*p],    o1 = sVf[2*p+1];
                    sCv[p] = (__builtin_fabsf(v0 - o0) <= 2e-4f * v0 &&
                              __builtin_fabsf(v1 - o1) <= 2e-4f * v1) ? 1.f : 0.f;
                    sVf[2*p] = v0; sVf[2*p+1] = v1;
                    svp[p] = packbf(v0, v1);
                }
            }
            __syncthreads();
            if (sCv[0] + sCv[1] + sCv[2] + sCv[3] + sCv[4] == 5.f) break;
        }

        // ---- dT phase: dd = u*E*v - T; dots; planes <- dd(bf16) ----
        {
            float vv[MN];
            #pragma unroll
            for (int p = 0; p < 5; ++p) {
                unsigned w = svp[p];
                vv[2*p] = bflo(w); vv[2*p+1] = bfhi(w);
            }
            float sMdT = 0.f, sCdT = 0.f, sCTdT = 0.f;
            #pragma unroll
            for (int k = 0; k < RPT; ++k) {
                const int r = tid + k * TPB;
                const float cp = (float)degi[r] * invn;
                const size_t b5 = (size_t)r * 5;
                const float u = uu[k];
                uint4 q = PL4x[r]; unsigned b4 = PL1x[r];
                float e[MN], dd[MN];
                e[0]=bflo(q.x); e[1]=bfhi(q.x); e[2]=bflo(q.y); e[3]=bfhi(q.y);
                e[4]=bflo(q.z); e[5]=bfhi(q.z); e[6]=bflo(q.w); e[7]=bfhi(q.w);
                e[8]=bflo(b4);  e[9]=bfhi(b4);
                #pragma unroll
                for (int h = 0; h < 5; ++h) {
                    unsigned tw = Tb[b5 + h], cw = Cb[b5 + h];
                    float2 mv = *(const float2*)(Mb + (size_t)r * MN + 2*h);
                    float d0 = u * e[2*h]   * vv[2*h]   - bflo(tw);
                    float d1 = u * e[2*h+1] * vv[2*h+1] - bfhi(tw);
                    dd[2*h] = d0; dd[2*h+1] = d1;
                    sMdT  += mv.x * d0 + mv.y * d1;
                    sCdT  += (cp + scq[2*h]) * d0 + (cp + scq[2*h+1]) * d1;
                    sCTdT += bflo(cw) * d0 + bfhi(cw) * d1;
                }
                PL4x[r] = make_uint4(packbf(dd[0],dd[1]), packbf(dd[2],dd[3]),
                                     packbf(dd[4],dd[5]), packbf(dd[6],dd[7]));
                PL1x[r] = packbf(dd[8], dd[9]);
            }
            #pragma unroll
            for (int d = 32; d; d >>= 1) {
                sMdT  += __shfl_xor(sMdT, d);
                sCdT  += __shfl_xor(sCdT, d);
                sCTdT += __shfl_xor(sCTdT, d);
            }
            if ((tid & 63) == 0) {
                const int w = tid >> 6;
                sRed[w] = sMdT; sRed[NW + w] = sCdT; sRed[2*NW + w] = sCTdT;
            }
            __syncthreads();   // dots staged AND dd planes visible block-wide
            if (tid == 0) {
                float r0 = 0.f, r1 = 0.f, r2 = 0.f;
                for (int w = 0; w < NW; ++w) { r0 += sRed[w]; r1 += sRed[NW+w]; r2 += sRed[2*NW+w]; }
                sDots[0] = r0; sDots[1] = r1; sDots[2] = r2;
            }
        }

        // ---- SpMM: D = C1 dT C2 (gather dd planes), sA = <D,dd>; Db <- bf16 ----
        {
            float dot = 0.f;
            #pragma unroll
            for (int k = 0; k < RPT; ++k) {
                const int r = tid + k * TPB;
                float y[MN];
                #pragma unroll
                for (int j = 0; j < MN; ++j) y[j] = 0.f;
                const int st = rowst[r], dg = degi[r];
                const unsigned short* cl = colix + st;
                for (int e = 0; e < dg; ++e) {
                    const int j = cl[e];
                    uint4 q = PL4x[j]; unsigned b4 = PL1x[j];
                    y[0] += bflo(q.x); y[1] += bfhi(q.x);
                    y[2] += bflo(q.y); y[3] += bfhi(q.y);
                    y[4] += bflo(q.z); y[5] += bfhi(q.z);
                    y[6] += bflo(q.w); y[7] += bfhi(q.w);
                    y[8] += bflo(b4);  y[9] += bfhi(b4);
                }
                uint4 q = PL4x[r]; unsigned b4 = PL1x[r];
                float dd[MN];
                dd[0]=bflo(q.x); dd[1]=bfhi(q.x); dd[2]=bflo(q.y); dd[3]=bfhi(q.y);
                dd[4]=bflo(q.z); dd[5]=bfhi(q.z); dd[6]=bflo(q.w); dd[7]=bfhi(q.w);
                dd[8]=bflo(b4);  dd[9]=bfhi(b4);
                #pragma unroll
                for (int h = 0; h < 5; ++h) {
                    float o0 = 0.f, o1 = 0.f;
                    #pragma unroll
                    for (int j = 0; j < MN; ++j) {
                        o0 += y[j] * sC2[j * MN + 2*h];
                        o1 += y[j] * sC2[j * MN + 2*h + 1];
                    }
                    dot += o0 * dd[2*h] + o1 * dd[2*h+1];
                    Db[(size_t)r * 5 + h] = packbf(o0, o1);
                }
            }
            #pragma unroll
            for (int d = 32; d; d >>= 1) dot += __shfl_xor(dot, d);
            if ((tid & 63) == 0) sRed[tid >> 6] = dot;
            __syncthreads();
            if (tid == 0) {
                float s = 0.f;
                for (int w = 0; w < NW; ++w) s += sRed[w];
                sDots[3] = s;
            }
            __syncthreads();
        }
    }

    // ---- F: final tau + objective (T,C,D from bf16 globals; dd from planes) ----
    if (tid == 0) {
        float a = -2.f * alpha * sDots[3];
        float b = oma * sDots[0] + alpha * (sDots[1] - 4.f * sDots[2]);
        float tau;
        if (a > 0.f) tau = fminf(fmaxf(-b / (2.f * a + 1e-16f), 0.f), 1.f);
        else         tau = (a + b < 0.f) ? 1.f : 0.f;
        sBC[0] = tau;
    }
    __syncthreads();
    {
        const float tau = sBC[0];
        float gw = 0.f, wass = 0.f;
        #pragma unroll
        for (int k = 0; k < RPT; ++k) {
            const int r = tid + k * TPB;
            const float cp = (float)degi[r] * invn;
            const size_t b5 = (size_t)r * 5;
            uint4 q = PL4x[r]; unsigned b4 = PL1x[r];
            float dd[MN];
            dd[0]=bflo(q.x); dd[1]=bfhi(q.x); dd[2]=bflo(q.y); dd[3]=bfhi(q.y);
            dd[4]=bflo(q.z); dd[5]=bfhi(q.z); dd[6]=bflo(q.w); dd[7]=bfhi(q.w);
            dd[8]=bflo(b4);  dd[9]=bfhi(b4);
            #pragma unroll
            for (int h = 0; h < 5; ++h) {
                unsigned tw = Tb[b5 + h], cw = Cb[b5 + h], Dw = Db[b5 + h];
                float2 mv = *(const float2*)(Mb + (size_t)r * MN + 2*h);
                float Tf0 = bflo(tw) + tau * dd[2*h];
                float Tf1 = bfhi(tw) + tau * dd[2*h+1];
                float Cf0 = bflo(cw) + tau * bflo(Dw);
                float Cf1 = bfhi(cw) + tau * bfhi(Dw);
                gw   += (cp + scq[2*h]   - 2.f * Cf0) * Tf0
                      + (cp + scq[2*h+1] - 2.f * Cf1) * Tf1;
                wass += mv.x * Tf0 + mv.y * Tf1;
            }
        }
        #pragma unroll
        for (int d = 32; d; d >>= 1) {
            gw   += __shfl_xor(gw, d);
            wass += __shfl_xor(wass, d);
        }
        if ((tid & 63) == 0) { sRed[tid >> 6] = gw; sRed[NW + (tid >> 6)] = wass; }
        __syncthreads();
        if (tid == 0) {
            float g = 0.f, ws = 0.f;
            for (int w = 0; w < NW; ++w) { g += sRed[w]; ws += sRed[NW + w]; }
            out[t] = oma * ws + alpha * g;
        }
    }
}

extern "C" void kernel_launch(void* const* d_in, const int* in_sizes, int n_in,
                              void* d_out, int out_size, void* d_ws, size_t ws_size,
                              hipStream_t stream) {
    const float* x   = (const float*)d_in[0];
    const void*  ei  = d_in[1];
    const float* tpl = (const float*)d_in[2];
    const float* tfp = (const float*)d_in[3];
    const float* q0  = (const float*)d_in[4];
    const float* a0  = (const float*)d_in[5];
    float* outp = (float*)d_out;
    float* Wp   = (float*)d_ws;
    (void)hipFuncSetAttribute(reinterpret_cast<const void*>(&tfgw_kernel),
                              hipFuncAttributeMaxDynamicSharedMemorySize, LDS_DYN);
    void* args[] = { &x, &ei, &tpl, &tfp, &q0, &a0, &outp, &Wp };
    hipLaunchCooperativeKernel(reinterpret_cast<const void*>(&tfgw_kernel),
                               dim3(NBLK), dim3(TPB), args, LDS_DYN, stream);
}